// Round 8
// baseline (362.163 us; speedup 1.0000x reference)
//
#include <hip/hip_runtime.h>
#include <cstdint>

#define N_NODES 50000
#define B_SZ 4
#define C_IN 32
#define C_OUT 64
#define K_CHEB 6
#define M_POOL 12500
#define NT_ROWS (N_NODES + M_POOL)
#define NS32 ((size_t)N_NODES * C_IN)
#define ZS ((size_t)N_NODES * C_OUT)

typedef __bf16 bf16x8 __attribute__((ext_vector_type(8)));
typedef float f32x4 __attribute__((ext_vector_type(4)));
typedef unsigned short ushort_t;

__device__ __forceinline__ unsigned short f2bf(float f) {
    union { float f; unsigned int u; } v;
    v.f = f;
    unsigned int r = v.u + 0x7fffu + ((v.u >> 16) & 1u);
    return (unsigned short)(r >> 16);
}

__device__ __forceinline__ float bf2f_lo(unsigned int u) {
    union { unsigned int u; float f; } v;
    v.u = u << 16;
    return v.f;
}

__device__ __forceinline__ float bf2f_hi(unsigned int u) {
    union { unsigned int u; float f; } v;
    v.u = u & 0xffff0000u;
    return v.f;
}

__device__ __forceinline__ unsigned int packbf(float a, float b) {
    return (unsigned int)f2bf(a) | ((unsigned int)f2bf(b) << 16);
}

// ---------------- Combined CSR build (rows 0..N-1 = graph, N..N+M-1 = pool) ----------------
// degree count whose atomicAdd return value IS the within-row slot (saves a second atomic pass)
__global__ void deg_slot_kernel(const int* __restrict__ row, const int* __restrict__ prow,
                                int* __restrict__ deg, int* __restrict__ slot, int E, int P) {
    int e = blockIdx.x * blockDim.x + threadIdx.x;
    if (e < E) slot[e] = atomicAdd(&deg[row[e]], 1);
    else if (e < E + P) slot[e] = atomicAdd(&deg[N_NODES + prow[e - E]], 1);
}

// dis for graph rows; padded degree: graph rows pad to multiple of 16, pool rows unpadded
__global__ void disdegp_kernel(const int* __restrict__ deg, float* __restrict__ dis,
                               int* __restrict__ degp) {
    int i = blockIdx.x * blockDim.x + threadIdx.x;
    if (i < N_NODES) {
        int d = deg[i];
        dis[i] = d > 0 ? rsqrtf((float)d) : 0.f;
        degp[i] = (d + 15) & ~15;
    } else if (i < NT_ROWS) {
        degp[i] = deg[i];
    }
}

__global__ void block_sum_kernel(const int* __restrict__ degp, int* __restrict__ bsum, int N) {
    __shared__ int sm[256];
    int i = blockIdx.x * 256 + threadIdx.x;
    sm[threadIdx.x] = (i < N) ? degp[i] : 0;
    __syncthreads();
    for (int s = 128; s > 0; s >>= 1) {
        if (threadIdx.x < s) sm[threadIdx.x] += sm[threadIdx.x + s];
        __syncthreads();
    }
    if (threadIdx.x == 0) bsum[blockIdx.x] = sm[0];
}

__global__ void scan_bsum_kernel(int* bsum, int nb, int* rowptr, int N) {
    if (blockIdx.x == 0 && threadIdx.x == 0) {
        int run = 0;
        for (int i = 0; i < nb; i++) { int v = bsum[i]; bsum[i] = run; run += v; }
        rowptr[N] = run;
    }
}

__global__ void rowptr_kernel(const int* __restrict__ degp, const int* __restrict__ bsum,
                              int* __restrict__ rowptr, int N) {
    __shared__ int sm[256];
    int i = blockIdx.x * 256 + threadIdx.x;
    sm[threadIdx.x] = (i < N) ? degp[i] : 0;
    __syncthreads();
    if (threadIdx.x == 0) {
        int run = bsum[blockIdx.x];
        for (int t = 0; t < 256; t++) { int v = sm[t]; sm[t] = run; run += v; }
    }
    __syncthreads();
    if (i < N) rowptr[i] = sm[threadIdx.x];
}

// atomic-free placement: pos = rowptr[r] + precomputed slot
__global__ void place_all_kernel(const int* __restrict__ row, const int* __restrict__ col,
                                 const int* __restrict__ prow, const int* __restrict__ pcol,
                                 const float* __restrict__ pval, const float* __restrict__ dis,
                                 const int* __restrict__ rowptr, const int* __restrict__ slot,
                                 int2* __restrict__ cn, int E, int P) {
    int e = blockIdx.x * blockDim.x + threadIdx.x;
    if (e < E) {
        int r = row[e], c = col[e];
        cn[rowptr[r] + slot[e]] = make_int2(c, __float_as_int(-dis[r] * dis[c]));
    } else if (e < E + P) {
        int i = e - E;
        int r = N_NODES + prow[i];
        cn[rowptr[r] + slot[e]] = make_int2(pcol[i], __float_as_int(pval[i]));
    }
}

// ---------------- fp32 -> bf16 cast ----------------
__global__ void cast_bf_kernel(const float* __restrict__ in, unsigned int* __restrict__ out,
                               int n2) {
    int i = blockIdx.x * 256 + threadIdx.x;
    if (i < n2) {
        float a = in[2 * i], b = in[2 * i + 1];
        out[i] = packbf(a, b);
    }
}

// ---------------- Chebyshev propagation v8 ----------------
// thread = (row, channel-pair); rows padded to multiples of 16 (dummy norm=0):
// most rows are a single straight-line batch of 16 independent gathers in flight.
// block = 16 rows of ONE batch (bid&3 -> per-XCD 3.2 MB batch slice stays L2-resident).
__global__ void prop_kernel(const ushort_t* __restrict__ hbf, const ushort_t* __restrict__ p2bf,
                            ushort_t* __restrict__ outbf,
                            const int* __restrict__ rowptr, const int2* __restrict__ cn,
                            float alpha) {
    int bid = blockIdx.x;
    int b = bid & 3;
    int grp = bid >> 2;            // [0, 3125)
    int lr = threadIdx.x >> 4;     // 0..15
    int cp = threadIdx.x & 15;     // channel pair
    int r = grp * 16 + lr;
    const char* hb = (const char*)hbf + (size_t)b * NS32 * 2;
    unsigned coff = (unsigned)cp * 4u;
    int p0 = rowptr[r], p1 = rowptr[r + 1];
    float a0 = 0.f, a1 = 0.f;
    for (int p = p0; p < p1; p += 16) {
        int2 ea[16];
#pragma unroll
        for (int i = 0; i < 16; i++) ea[i] = cn[p + i];
        unsigned v[16];
#pragma unroll
        for (int i = 0; i < 16; i++)
            v[i] = *(const unsigned*)(hb + (((unsigned)ea[i].x << 6) + coff));
#pragma unroll
        for (int i = 0; i < 16; i++) {
            float n = __int_as_float(ea[i].y);
            a0 += bf2f_lo(v[i]) * n;
            a1 += bf2f_hi(v[i]) * n;
        }
    }
    unsigned ooff = ((unsigned)r << 6) + coff;
    float v0 = alpha * a0, v1 = alpha * a1;
    if (p2bf) {
        unsigned pv = *(const unsigned*)((const char*)p2bf + (size_t)b * NS32 * 2 + ooff);
        v0 -= bf2f_lo(pv);
        v1 -= bf2f_hi(pv);
    }
    *(unsigned*)((char*)outbf + (size_t)b * NS32 * 2 + ooff) = packbf(v0, v1);
}

// ---------------- W pack: [s][t][lane][j] bf16 fragment order ----------------
__global__ void packW_kernel(const float* __restrict__ W, ushort_t* __restrict__ Wp) {
    int i = blockIdx.x * 256 + threadIdx.x;
    if (i >= K_CHEB * 4 * 64 * 8) return;
    int j = i & 7;
    int lane = (i >> 3) & 63;
    int t = (i >> 9) & 3;
    int s = i >> 11;
    int k = (lane >> 4) * 8 + j;
    int col = t * 16 + (lane & 15);
    Wp[i] = f2bf(W[((size_t)s * C_IN + k) * C_OUT + col]);
}

// ---------------- Fused 3-source MFMA GEMM ----------------
__global__ void gemm_mfma_kernel(const ushort_t* __restrict__ T0, const ushort_t* __restrict__ T1,
                                 const ushort_t* __restrict__ T2,
                                 const ushort_t* __restrict__ Wp,
                                 const float* __restrict__ bias, float* __restrict__ z,
                                 int second) {
    int lane = threadIdx.x & 63;
    int wave = (blockIdx.x << 2) + (threadIdx.x >> 6);
    int r0 = wave << 4;
    int ga = r0 + (lane & 15);
    int koff = (lane >> 4) * 8;
    const ushort_t* Ts[3] = {T0, T1, T2};

    bf16x8 afr[3];
#pragma unroll
    for (int s = 0; s < 3; s++)
        afr[s] = *(const bf16x8*)(Ts[s] + (size_t)ga * C_IN + koff);

    int orow = r0 + ((lane >> 4) << 2);
#pragma unroll
    for (int t = 0; t < 4; t++) {
        f32x4 acc = {0.f, 0.f, 0.f, 0.f};
#pragma unroll
        for (int s = 0; s < 3; s++) {
            bf16x8 bfr = *(const bf16x8*)(Wp + (((s << 2) + t) * 64 + lane) * 8);
            acc = __builtin_amdgcn_mfma_f32_16x16x32_bf16(afr[s], bfr, acc, 0, 0, 0);
        }
        int col = (t << 4) + (lane & 15);
        float bv = bias[col];
#pragma unroll
        for (int rg = 0; rg < 4; rg++) {
            size_t idx = (size_t)(orow + rg) * C_OUT + col;
            float v = acc[rg];
            if (!second) {
                z[idx] = v + bv;
            } else {
                v += z[idx];
                z[idx] = v > 0.f ? v : (expf(v) - 1.f);
            }
        }
    }
}

// ---------------- Pool: deterministic CSR gather-reduce (combined rowptr, rows N..N+M-1) ----
__global__ void pool_csr_kernel(const float* __restrict__ z, const int* __restrict__ rowptr,
                                const int2* __restrict__ cn, float* __restrict__ out) {
    int r = blockIdx.x * 4 + (threadIdx.x >> 6);
    int c = threadIdx.x & 63;
    if (r >= M_POOL) return;
    const char* z0 = (const char*)z;
    const char* z1 = z0 + ZS * 4;
    const char* z2 = z0 + 2 * ZS * 4;
    const char* z3 = z0 + 3 * ZS * 4;
    unsigned coff = (unsigned)c << 2;
    float a0 = 0.f, a1 = 0.f, a2 = 0.f, a3 = 0.f;
    int p0 = rowptr[N_NODES + r], p1 = rowptr[N_NODES + r + 1];
    for (int p = p0; p < p1; ++p) {
        int2 e = cn[p];
        float v = __int_as_float(e.y);
        unsigned off = ((unsigned)e.x << 8) + coff;
        a0 += *(const float*)(z0 + off) * v;
        a1 += *(const float*)(z1 + off) * v;
        a2 += *(const float*)(z2 + off) * v;
        a3 += *(const float*)(z3 + off) * v;
    }
    size_t idx = (size_t)r * C_OUT + c;
    out[idx]                           = a0;
    out[idx + (size_t)M_POOL * 64]     = a1;
    out[idx + 2 * (size_t)M_POOL * 64] = a2;
    out[idx + 3 * (size_t)M_POOL * 64] = a3;
}

extern "C" void kernel_launch(void* const* d_in, const int* in_sizes, int n_in,
                              void* d_out, int out_size, void* d_ws, size_t ws_size,
                              hipStream_t stream) {
    const float* x    = (const float*)d_in[0];
    const int*   ei   = (const int*)d_in[1];
    const int*   prow = (const int*)d_in[2];
    const int*   pcol = (const int*)d_in[3];
    const float* pval = (const float*)d_in[4];
    const float* W    = (const float*)d_in[5];
    const float* bias = (const float*)d_in[6];
    const int E = in_sizes[1] / 2;
    const int P = in_sizes[2];
    const int* row = ei;
    const int* col = ei + E;
    const int EP_MAX = E + 15 * N_NODES + P;  // 16-padded CSR upper bound

    char* ws = (char*)d_ws;
    size_t o = 0;
    auto alloc = [&](size_t bytes) -> char* {
        char* p = ws + o;
        o += (bytes + 255) & ~(size_t)255;
        return p;
    };
    int nb = (NT_ROWS + 255) / 256;
    int*   deg    = (int*)alloc((size_t)NT_ROWS * 4);
    int*   degp   = (int*)alloc((size_t)NT_ROWS * 4);
    float* dis    = (float*)alloc((size_t)N_NODES * 4);
    int*   rowptr = (int*)alloc((size_t)(NT_ROWS + 1) * 4);
    int*   slot   = (int*)alloc((size_t)(E + P) * 4);
    int*   bsum   = (int*)alloc((size_t)nb * 4);
    int2*  cn     = (int2*)alloc((size_t)EP_MAX * 8);
    ushort_t* Wp  = (ushort_t*)alloc((size_t)K_CHEB * 4 * 64 * 8 * 2);
    ushort_t* xbf = (ushort_t*)alloc((size_t)B_SZ * NS32 * 2);
    ushort_t* bfA = (ushort_t*)alloc((size_t)B_SZ * NS32 * 2);
    ushort_t* bfB = (ushort_t*)alloc((size_t)B_SZ * NS32 * 2);
    ushort_t* bfC = (ushort_t*)alloc((size_t)B_SZ * NS32 * 2);
    float*    z   = (float*)alloc((size_t)B_SZ * N_NODES * C_OUT * 4);

    hipMemsetAsync(deg, 0, (size_t)NT_ROWS * 4, stream);
    hipMemsetAsync(cn, 0, (size_t)EP_MAX * 8, stream);  // pad entries -> col 0, norm 0.0

    // combined CSR build (single atomic pass; atomicAdd return = slot)
    deg_slot_kernel<<<(E + P + 255) / 256, 256, 0, stream>>>(row, prow, deg, slot, E, P);
    disdegp_kernel<<<nb, 256, 0, stream>>>(deg, dis, degp);
    block_sum_kernel<<<nb, 256, 0, stream>>>(degp, bsum, NT_ROWS);
    scan_bsum_kernel<<<1, 64, 0, stream>>>(bsum, nb, rowptr, NT_ROWS);
    rowptr_kernel<<<nb, 256, 0, stream>>>(degp, bsum, rowptr, NT_ROWS);
    place_all_kernel<<<(E + P + 255) / 256, 256, 0, stream>>>(row, col, prow, pcol, pval, dis,
                                                              rowptr, slot, cn, E, P);
    // W pack + x cast
    packW_kernel<<<(K_CHEB * 4 * 64 * 8 + 255) / 256, 256, 0, stream>>>(W, Wp);
    int n2 = (int)(B_SZ * NS32 / 2);
    cast_bf_kernel<<<(n2 + 255) / 256, 256, 0, stream>>>(x, (unsigned int*)xbf, n2);

    int prop_blocks = (N_NODES / 16) * B_SZ;    // 12500
    int gemm_blocks = (B_SZ * N_NODES) / 64;    // 3125

    // T1 = prop(x); T2 = 2*prop(T1) - x
    prop_kernel<<<prop_blocks, 256, 0, stream>>>(xbf, nullptr, bfA, rowptr, cn, 1.0f);
    prop_kernel<<<prop_blocks, 256, 0, stream>>>(bfA, xbf, bfB, rowptr, cn, 2.0f);
    // z = [x,T1,T2] @ W[0:3] + bias
    gemm_mfma_kernel<<<gemm_blocks, 256, 0, stream>>>(xbf, bfA, bfB, Wp, bias, z, 0);
    // T3, T4, T5
    prop_kernel<<<prop_blocks, 256, 0, stream>>>(bfB, bfA, bfC, rowptr, cn, 2.0f);
    prop_kernel<<<prop_blocks, 256, 0, stream>>>(bfC, bfB, bfA, rowptr, cn, 2.0f);
    prop_kernel<<<prop_blocks, 256, 0, stream>>>(bfA, bfC, bfB, rowptr, cn, 2.0f);
    // z = ELU(z + [T3,T4,T5] @ W[3:6])
    gemm_mfma_kernel<<<gemm_blocks, 256, 0, stream>>>(bfC, bfA, bfB, Wp + 3 * 4 * 64 * 8,
                                                      bias, z, 1);
    // pool
    pool_csr_kernel<<<(M_POOL + 3) / 4, 256, 0, stream>>>(z, rowptr, cn, (float*)d_out);
}

// Round 9
// 336.372 us; speedup vs baseline: 1.0767x; 1.0767x over previous
//
#include <hip/hip_runtime.h>
#include <hip/hip_fp16.h>
#include <cstdint>

#define N_NODES 50000
#define B_SZ 4
#define C_IN 32
#define C_OUT 64
#define K_CHEB 6
#define M_POOL 12500
#define NT_ROWS (N_NODES + M_POOL)
#define NS32 ((size_t)N_NODES * C_IN)
#define ZS ((size_t)N_NODES * C_OUT)

typedef _Float16 f16x8 __attribute__((ext_vector_type(8)));
typedef float f32x4 __attribute__((ext_vector_type(4)));
typedef unsigned short ushort_t;

__device__ __forceinline__ unsigned short f2h(float f) {
    union { _Float16 h; unsigned short u; } v;
    v.h = (_Float16)f;
    return v.u;
}

// ---------------- Combined CSR build (rows 0..N-1 = graph, N..N+M-1 = pool) ----------------
__global__ void deg_slot_kernel(const int* __restrict__ row, const int* __restrict__ prow,
                                int* __restrict__ deg, int* __restrict__ slot, int E, int P) {
    int e = blockIdx.x * blockDim.x + threadIdx.x;
    if (e < E) slot[e] = atomicAdd(&deg[row[e]], 1);
    else if (e < E + P) slot[e] = atomicAdd(&deg[N_NODES + prow[e - E]], 1);
}

// dis for graph rows; padded degree: graph rows pad to multiple of 8, pool rows unpadded
__global__ void disdegp_kernel(const int* __restrict__ deg, float* __restrict__ dis,
                               int* __restrict__ degp) {
    int i = blockIdx.x * blockDim.x + threadIdx.x;
    if (i < N_NODES) {
        int d = deg[i];
        dis[i] = d > 0 ? rsqrtf((float)d) : 0.f;
        degp[i] = (d + 7) & ~7;
    } else if (i < NT_ROWS) {
        degp[i] = deg[i];
    }
}

__global__ void block_sum_kernel(const int* __restrict__ degp, int* __restrict__ bsum, int N) {
    __shared__ int sm[256];
    int i = blockIdx.x * 256 + threadIdx.x;
    sm[threadIdx.x] = (i < N) ? degp[i] : 0;
    __syncthreads();
    for (int s = 128; s > 0; s >>= 1) {
        if (threadIdx.x < s) sm[threadIdx.x] += sm[threadIdx.x + s];
        __syncthreads();
    }
    if (threadIdx.x == 0) bsum[blockIdx.x] = sm[0];
}

__global__ void scan_bsum_kernel(int* bsum, int nb, int* rowptr, int N) {
    if (blockIdx.x == 0 && threadIdx.x == 0) {
        int run = 0;
        for (int i = 0; i < nb; i++) { int v = bsum[i]; bsum[i] = run; run += v; }
        rowptr[N] = run;
    }
}

__global__ void rowptr_kernel(const int* __restrict__ degp, const int* __restrict__ bsum,
                              int* __restrict__ rowptr, int N) {
    __shared__ int sm[256];
    int i = blockIdx.x * 256 + threadIdx.x;
    sm[threadIdx.x] = (i < N) ? degp[i] : 0;
    __syncthreads();
    if (threadIdx.x == 0) {
        int run = bsum[blockIdx.x];
        for (int t = 0; t < 256; t++) { int v = sm[t]; sm[t] = run; run += v; }
    }
    __syncthreads();
    if (i < N) rowptr[i] = sm[threadIdx.x];
}

// atomic-free placement. Graph rows: cn.y = packed half2(norm,norm). Pool rows: cn.y = f32 bits.
__global__ void place_all_kernel(const int* __restrict__ row, const int* __restrict__ col,
                                 const int* __restrict__ prow, const int* __restrict__ pcol,
                                 const float* __restrict__ pval, const float* __restrict__ dis,
                                 const int* __restrict__ rowptr, const int* __restrict__ slot,
                                 int2* __restrict__ cn, int E, int P) {
    int e = blockIdx.x * blockDim.x + threadIdx.x;
    if (e < E) {
        int r = row[e], c = col[e];
        float nm = -dis[r] * dis[c];
        unsigned h = f2h(nm);
        cn[rowptr[r] + slot[e]] = make_int2(c, (int)(h | (h << 16)));
    } else if (e < E + P) {
        int i = e - E;
        int r = N_NODES + prow[i];
        cn[rowptr[r] + slot[e]] = make_int2(pcol[i], __float_as_int(pval[i]));
    }
}

// ---------------- fp32 -> fp16 cast (2 elements/thread) ----------------
__global__ void cast_h_kernel(const float* __restrict__ in, unsigned int* __restrict__ out,
                              int n2) {
    int i = blockIdx.x * 256 + threadIdx.x;
    if (i < n2) {
        unsigned a = f2h(in[2 * i]), b = f2h(in[2 * i + 1]);
        out[i] = a | (b << 16);
    }
}

// ---------------- Chebyshev propagation v9: fp16 packed math ----------------
// thread = (row, channel-quad): 8 lanes/row, each gathers 8B (4 ch = 2 half2) per edge,
// 2 x v_pk_fma_f16 per edge. Rows padded to multiples of 8 (dummy norm=0).
// 8-deep gather ILP + cn prefetch pipeline; block = 32 rows of ONE batch (bid&3
// -> per-XCD 3.2 MB batch slice stays L2-resident).
__global__ void prop_kernel(const ushort_t* __restrict__ hf, const ushort_t* __restrict__ p2f,
                            ushort_t* __restrict__ outf,
                            const int* __restrict__ rowptr, const int2* __restrict__ cn,
                            float alpha) {
    int bid = blockIdx.x;
    int b = bid & 3;
    int grp = bid >> 2;            // [0, 1563)
    int lr = threadIdx.x >> 3;     // 0..31
    int cq = threadIdx.x & 7;      // channel quad: channels 4cq .. 4cq+3
    int r = grp * 32 + lr;
    if (r >= N_NODES) return;
    const char* hb = (const char*)hf + (size_t)b * NS32 * 2;
    unsigned coff = (unsigned)cq * 8u;
    int p0 = rowptr[r], p1 = rowptr[r + 1];
    __half2 a01 = __float2half2_rn(0.f);
    __half2 a23 = __float2half2_rn(0.f);
    if (p0 < p1) {
        int2 ea[8];
#pragma unroll
        for (int i = 0; i < 8; i++) ea[i] = cn[p0 + i];
        int p = p0 + 8;
        for (; p < p1; p += 8) {
            uint2 v[8];
#pragma unroll
            for (int i = 0; i < 8; i++)
                v[i] = *(const uint2*)(hb + (((unsigned)ea[i].x << 6) + coff));
            int2 eb[8];
#pragma unroll
            for (int i = 0; i < 8; i++) eb[i] = cn[p + i];
#pragma unroll
            for (int i = 0; i < 8; i++) {
                __half2 n2 = __builtin_bit_cast(__half2, ea[i].y);
                a01 = __hfma2(__builtin_bit_cast(__half2, v[i].x), n2, a01);
                a23 = __hfma2(__builtin_bit_cast(__half2, v[i].y), n2, a23);
            }
#pragma unroll
            for (int i = 0; i < 8; i++) ea[i] = eb[i];
        }
        uint2 v[8];
#pragma unroll
        for (int i = 0; i < 8; i++)
            v[i] = *(const uint2*)(hb + (((unsigned)ea[i].x << 6) + coff));
#pragma unroll
        for (int i = 0; i < 8; i++) {
            __half2 n2 = __builtin_bit_cast(__half2, ea[i].y);
            a01 = __hfma2(__builtin_bit_cast(__half2, v[i].x), n2, a01);
            a23 = __hfma2(__builtin_bit_cast(__half2, v[i].y), n2, a23);
        }
    }
    unsigned ooff = ((unsigned)r << 6) + coff;
    uint2 o;
    if (p2f) {
        __half2 al2 = __float2half2_rn(alpha);
        uint2 pv = *(const uint2*)((const char*)p2f + (size_t)b * NS32 * 2 + ooff);
        __half2 o01 = __hfma2(a01, al2, __hneg2(__builtin_bit_cast(__half2, pv.x)));
        __half2 o23 = __hfma2(a23, al2, __hneg2(__builtin_bit_cast(__half2, pv.y)));
        o.x = __builtin_bit_cast(unsigned, o01);
        o.y = __builtin_bit_cast(unsigned, o23);
    } else {
        o.x = __builtin_bit_cast(unsigned, a01);
        o.y = __builtin_bit_cast(unsigned, a23);
    }
    *(uint2*)((char*)outf + (size_t)b * NS32 * 2 + ooff) = o;
}

// ---------------- W pack: [s][t][lane][j] fp16 fragment order ----------------
__global__ void packW_kernel(const float* __restrict__ W, ushort_t* __restrict__ Wp) {
    int i = blockIdx.x * 256 + threadIdx.x;
    if (i >= K_CHEB * 4 * 64 * 8) return;
    int j = i & 7;
    int lane = (i >> 3) & 63;
    int t = (i >> 9) & 3;
    int s = i >> 11;
    int k = (lane >> 4) * 8 + j;
    int col = t * 16 + (lane & 15);
    Wp[i] = f2h(W[((size_t)s * C_IN + k) * C_OUT + col]);
}

// ---------------- Fused 3-source MFMA GEMM (fp16 inputs, f32 accum) ----------------
__global__ void gemm_mfma_kernel(const ushort_t* __restrict__ T0, const ushort_t* __restrict__ T1,
                                 const ushort_t* __restrict__ T2,
                                 const ushort_t* __restrict__ Wp,
                                 const float* __restrict__ bias, float* __restrict__ z,
                                 int second) {
    int lane = threadIdx.x & 63;
    int wave = (blockIdx.x << 2) + (threadIdx.x >> 6);
    int r0 = wave << 4;
    int ga = r0 + (lane & 15);
    int koff = (lane >> 4) * 8;
    const ushort_t* Ts[3] = {T0, T1, T2};

    f16x8 afr[3];
#pragma unroll
    for (int s = 0; s < 3; s++)
        afr[s] = *(const f16x8*)(Ts[s] + (size_t)ga * C_IN + koff);

    int orow = r0 + ((lane >> 4) << 2);
#pragma unroll
    for (int t = 0; t < 4; t++) {
        f32x4 acc = {0.f, 0.f, 0.f, 0.f};
#pragma unroll
        for (int s = 0; s < 3; s++) {
            f16x8 bfr = *(const f16x8*)(Wp + (((s << 2) + t) * 64 + lane) * 8);
            acc = __builtin_amdgcn_mfma_f32_16x16x32_f16(afr[s], bfr, acc, 0, 0, 0);
        }
        int col = (t << 4) + (lane & 15);
        float bv = bias[col];
#pragma unroll
        for (int rg = 0; rg < 4; rg++) {
            size_t idx = (size_t)(orow + rg) * C_OUT + col;
            float v = acc[rg];
            if (!second) {
                z[idx] = v + bv;
            } else {
                v += z[idx];
                z[idx] = v > 0.f ? v : (expf(v) - 1.f);
            }
        }
    }
}

// ---------------- Pool: deterministic CSR gather-reduce (combined rowptr, rows N..N+M-1) ----
__global__ void pool_csr_kernel(const float* __restrict__ z, const int* __restrict__ rowptr,
                                const int2* __restrict__ cn, float* __restrict__ out) {
    int r = blockIdx.x * 4 + (threadIdx.x >> 6);
    int c = threadIdx.x & 63;
    if (r >= M_POOL) return;
    const char* z0 = (const char*)z;
    const char* z1 = z0 + ZS * 4;
    const char* z2 = z0 + 2 * ZS * 4;
    const char* z3 = z0 + 3 * ZS * 4;
    unsigned coff = (unsigned)c << 2;
    float a0 = 0.f, a1 = 0.f, a2 = 0.f, a3 = 0.f;
    int p0 = rowptr[N_NODES + r], p1 = rowptr[N_NODES + r + 1];
    for (int p = p0; p < p1; ++p) {
        int2 e = cn[p];
        float v = __int_as_float(e.y);
        unsigned off = ((unsigned)e.x << 8) + coff;
        a0 += *(const float*)(z0 + off) * v;
        a1 += *(const float*)(z1 + off) * v;
        a2 += *(const float*)(z2 + off) * v;
        a3 += *(const float*)(z3 + off) * v;
    }
    size_t idx = (size_t)r * C_OUT + c;
    out[idx]                           = a0;
    out[idx + (size_t)M_POOL * 64]     = a1;
    out[idx + 2 * (size_t)M_POOL * 64] = a2;
    out[idx + 3 * (size_t)M_POOL * 64] = a3;
}

extern "C" void kernel_launch(void* const* d_in, const int* in_sizes, int n_in,
                              void* d_out, int out_size, void* d_ws, size_t ws_size,
                              hipStream_t stream) {
    const float* x    = (const float*)d_in[0];
    const int*   ei   = (const int*)d_in[1];
    const int*   prow = (const int*)d_in[2];
    const int*   pcol = (const int*)d_in[3];
    const float* pval = (const float*)d_in[4];
    const float* W    = (const float*)d_in[5];
    const float* bias = (const float*)d_in[6];
    const int E = in_sizes[1] / 2;
    const int P = in_sizes[2];
    const int* row = ei;
    const int* col = ei + E;
    const int EP_MAX = E + 7 * N_NODES + P;  // 8-padded CSR upper bound

    char* ws = (char*)d_ws;
    size_t o = 0;
    auto alloc = [&](size_t bytes) -> char* {
        char* p = ws + o;
        o += (bytes + 255) & ~(size_t)255;
        return p;
    };
    int nb = (NT_ROWS + 255) / 256;
    int*   deg    = (int*)alloc((size_t)NT_ROWS * 4);
    int*   degp   = (int*)alloc((size_t)NT_ROWS * 4);
    float* dis    = (float*)alloc((size_t)N_NODES * 4);
    int*   rowptr = (int*)alloc((size_t)(NT_ROWS + 1) * 4);
    int*   slot   = (int*)alloc((size_t)(E + P) * 4);
    int*   bsum   = (int*)alloc((size_t)nb * 4);
    int2*  cn     = (int2*)alloc((size_t)EP_MAX * 8);
    ushort_t* Wp  = (ushort_t*)alloc((size_t)K_CHEB * 4 * 64 * 8 * 2);
    ushort_t* xh  = (ushort_t*)alloc((size_t)B_SZ * NS32 * 2);
    ushort_t* hA  = (ushort_t*)alloc((size_t)B_SZ * NS32 * 2);
    ushort_t* hB  = (ushort_t*)alloc((size_t)B_SZ * NS32 * 2);
    ushort_t* hC  = (ushort_t*)alloc((size_t)B_SZ * NS32 * 2);
    float*    z   = (float*)alloc((size_t)B_SZ * N_NODES * C_OUT * 4);

    hipMemsetAsync(deg, 0, (size_t)NT_ROWS * 4, stream);
    hipMemsetAsync(cn, 0, (size_t)EP_MAX * 8, stream);  // pad entries -> col 0, norm 0.0

    // combined CSR build (single atomic pass; atomicAdd return = slot)
    deg_slot_kernel<<<(E + P + 255) / 256, 256, 0, stream>>>(row, prow, deg, slot, E, P);
    disdegp_kernel<<<nb, 256, 0, stream>>>(deg, dis, degp);
    block_sum_kernel<<<nb, 256, 0, stream>>>(degp, bsum, NT_ROWS);
    scan_bsum_kernel<<<1, 64, 0, stream>>>(bsum, nb, rowptr, NT_ROWS);
    rowptr_kernel<<<nb, 256, 0, stream>>>(degp, bsum, rowptr, NT_ROWS);
    place_all_kernel<<<(E + P + 255) / 256, 256, 0, stream>>>(row, col, prow, pcol, pval, dis,
                                                              rowptr, slot, cn, E, P);
    // W pack + x cast
    packW_kernel<<<(K_CHEB * 4 * 64 * 8 + 255) / 256, 256, 0, stream>>>(W, Wp);
    int n2 = (int)(B_SZ * NS32 / 2);
    cast_h_kernel<<<(n2 + 255) / 256, 256, 0, stream>>>(x, (unsigned int*)xh, n2);

    int prop_blocks = ((N_NODES + 31) / 32) * B_SZ;  // 1563 * 4 = 6252
    int gemm_blocks = (B_SZ * N_NODES) / 64;         // 3125

    // T1 = prop(x); T2 = 2*prop(T1) - x
    prop_kernel<<<prop_blocks, 256, 0, stream>>>(xh, nullptr, hA, rowptr, cn, 1.0f);
    prop_kernel<<<prop_blocks, 256, 0, stream>>>(hA, xh, hB, rowptr, cn, 2.0f);
    // z = [x,T1,T2] @ W[0:3] + bias
    gemm_mfma_kernel<<<gemm_blocks, 256, 0, stream>>>(xh, hA, hB, Wp, bias, z, 0);
    // T3, T4, T5
    prop_kernel<<<prop_blocks, 256, 0, stream>>>(hB, hA, hC, rowptr, cn, 2.0f);
    prop_kernel<<<prop_blocks, 256, 0, stream>>>(hC, hB, hA, rowptr, cn, 2.0f);
    prop_kernel<<<prop_blocks, 256, 0, stream>>>(hA, hC, hB, rowptr, cn, 2.0f);
    // z = ELU(z + [T3,T4,T5] @ W[3:6])
    gemm_mfma_kernel<<<gemm_blocks, 256, 0, stream>>>(hC, hA, hB, Wp + 3 * 4 * 64 * 8,
                                                      bias, z, 1);
    // pool
    pool_csr_kernel<<<(M_POOL + 3) / 4, 256, 0, stream>>>(z, rowptr, cn, (float*)d_out);
}